// Round 17
// baseline (570.400 us; speedup 1.0000x reference)
//
#include <hip/hip_runtime.h>
#include <hip/hip_bf16.h>
#include <stdint.h>

#define QTOT 10000
#define MPAD 10240
#define CDIM 256
#define ODIM 16384
#define RTOT 20096  // 157*128 : padded global rows (b*10000+q)

using f32x4  = __attribute__((ext_vector_type(4))) float;
using bf16x8 = __attribute__((ext_vector_type(8))) short;

// global -> LDS direct (16B/lane). LDS dest = wave-uniform base + lane*16.
#define GLOAD_LDS(gp, lp) __builtin_amdgcn_global_load_lds(                     \
    (const __attribute__((address_space(1))) unsigned int*)(gp),                \
    (__attribute__((address_space(3))) unsigned int*)(lp), 16, 0, 0)

static __device__ __forceinline__ short f2bs(float x) {
  __hip_bfloat16 h = __float2bfloat16(x);
  return *(short*)&h;
}

// ---------------- prep kernels ----------------
__global__ void cvt_f32_bf16(const float* __restrict__ s, __hip_bfloat16* __restrict__ d, int n) {
  for (int i = blockIdx.x * blockDim.x + threadIdx.x; i < n; i += gridDim.x * blockDim.x)
    d[i] = __float2bfloat16(s[i]);
}

// conv_w row-permute + cvt: dst row o_new = g*4096 + c2*64 + c1  <-  src row g*4096 + c1*64 + c2
__global__ void cvt_permute_cw(const float* __restrict__ s, __hip_bfloat16* __restrict__ d, int n) {
  for (int i = blockIdx.x * blockDim.x + threadIdx.x; i < n; i += gridDim.x * blockDim.x) {
    int rn = i >> 8, c = i & 255;
    int ro = (rn & ~4095) | ((rn & 63) << 6) | ((rn >> 6) & 63);
    d[i] = __float2bfloat16(s[ro * 256 + c]);
  }
}

// bev [b][c][q] f32 -> bevT [b][q][c] bf16, rows q>=QTOT zero-filled up to MPAD
__global__ __launch_bounds__(256) void transpose_bev(const float* __restrict__ bev,
                                                     __hip_bfloat16* __restrict__ bevT) {
  __shared__ float tl[32][33];
  int tx = threadIdx.x, ty = threadIdx.y;
  int q0 = blockIdx.x * 32, c0 = blockIdx.y * 32, b = blockIdx.z;
#pragma unroll
  for (int i = 0; i < 4; ++i) {
    int c = c0 + ty + i * 8, q = q0 + tx;
    tl[ty + i * 8][tx] = (q < QTOT) ? bev[((size_t)b * CDIM + c) * QTOT + q] : 0.0f;
  }
  __syncthreads();
#pragma unroll
  for (int i = 0; i < 4; ++i) {
    int q = q0 + ty + i * 8, c = c0 + tx;
    bevT[((size_t)b * MPAD + q) * CDIM + c] = __float2bfloat16(tl[tx][ty + i * 8]);
  }
}

// ---------------- fused: gemm_param[job j] (r14-verbatim) UNION mix_mfma[job j-1] (r4-verbatim)
// Roles interleaved by blockIdx parity -> each CU co-hosts one compute-heavy gemm block and one
// memory-heavy mix block (complementary pipes). mix reads Pin (prev chunk), gemm writes Pout.
__global__ __launch_bounds__(256) void gemm_mix(const __hip_bfloat16* __restrict__ bevT,
                                                const __hip_bfloat16* __restrict__ Bw,
                                                const float* __restrict__ convb,
                                                __hip_bfloat16* __restrict__ Pout,
                                                const __hip_bfloat16* __restrict__ Pin,
                                                const float* __restrict__ pts,
                                                const float* __restrict__ lng,
                                                const float* __restrict__ lnb,
                                                __hip_bfloat16* __restrict__ act,
                                                int ngemm, int nmix, int nbm,
                                                int bg, int q0g,
                                                int bmx, int q0m, int nvalidm) {
  __shared__ __align__(16) unsigned char smem[65536];
  int t = threadIdx.x, lane = t & 63, w = t >> 6;
  // role assignment: alternate over the first 2*min(ngemm,nmix) blocks, remainder single-role
  int mn = ngemm < nmix ? ngemm : nmix;
  int m2 = 2 * mn;
  int bid = blockIdx.x;
  bool isGemm;
  int rid;
  if (bid < m2) { isGemm = !(bid & 1); rid = bid >> 1; }
  else          { isGemm = (ngemm > nmix); rid = mn + (bid - m2); }

  if (isGemm) {
    // ================= gemm role (r14 gemm_param, id = rid over ngemm) =================
    int total = ngemm;
    int nid = (total & 7) ? rid : ((rid & 7) * (total >> 3) + (rid >> 3));
    int bm = nid % nbm, bn = nid / nbm;
    int wm = (w >> 1) * 64, wn = (w & 1) * 64;
    int l15 = lane & 15, hi = lane >> 4;
    int srow = lane >> 3;
    int kbs  = ((lane & 7) ^ srow) * 8;
    const __hip_bfloat16* A  = bevT + ((size_t)bg * MPAD + q0g) * CDIM;
    const __hip_bfloat16* pA = A  + (size_t)(bm * 128 + w * 32 + srow) * CDIM + kbs;
    const __hip_bfloat16* pB = Bw + (size_t)(bn * 128 + w * 32 + srow) * CDIM + kbs;
    f32x4 acc[4][4] = {};

#define LSA(buf) (smem + (buf) * 16384)
#define LSB(buf) (smem + 32768 + (buf) * 16384)
#define STAGE_P(buf, kt) do {                                                   \
    _Pragma("unroll")                                                           \
    for (int i = 0; i < 4; ++i) {                                               \
      GLOAD_LDS(pA + (size_t)i * 8 * CDIM + (kt), LSA(buf) + (w * 4 + i) * 1024); \
      GLOAD_LDS(pB + (size_t)i * 8 * CDIM + (kt), LSB(buf) + (w * 4 + i) * 1024); \
    } } while (0)

    STAGE_P(0, 0);
    asm volatile("s_waitcnt vmcnt(0)" ::: "memory");
    __builtin_amdgcn_s_barrier();
#pragma unroll
    for (int kt = 0; kt < 4; ++kt) {
      const int cur = kt & 1;
      if (kt < 3) STAGE_P(cur ^ 1, (kt + 1) * 64);
      __builtin_amdgcn_sched_barrier(0);
#pragma unroll
      for (int kk = 0; kk < 2; ++kk) {
        int kb = kk * 64 + (hi << 4);
        bf16x8 af[4], bfr[4];
#pragma unroll
        for (int mi = 0; mi < 4; ++mi) {
          int row = wm + mi * 16 + l15;
          af[mi] = *(const bf16x8*)(LSA(cur) + ((row * 128 + kb) ^ ((row & 7) << 4)));
        }
#pragma unroll
        for (int ni = 0; ni < 4; ++ni) {
          int row = wn + ni * 16 + l15;
          bfr[ni] = *(const bf16x8*)(LSB(cur) + ((row * 128 + kb) ^ ((row & 7) << 4)));
        }
#pragma unroll
        for (int mi = 0; mi < 4; ++mi)
#pragma unroll
          for (int ni = 0; ni < 4; ++ni)
            acc[mi][ni] = __builtin_amdgcn_mfma_f32_16x16x32_bf16(af[mi], bfr[ni], acc[mi][ni], 0, 0, 0);
      }
      __builtin_amdgcn_sched_barrier(0);
      if (kt < 3) asm volatile("s_waitcnt vmcnt(0)" ::: "memory");
      __builtin_amdgcn_s_barrier();
      __builtin_amdgcn_sched_barrier(0);
    }
    // coalesced epilogue: acc -> LDS [128][136] shorts -> dwordx4 stores
    short* st = (short*)smem;
#pragma unroll
    for (int ni = 0; ni < 4; ++ni) {
      int colL = wn + ni * 16 + l15;
      int col  = bn * 128 + colL;
      int o_old = (col & ~4095) | ((col & 63) << 6) | ((col >> 6) & 63);
      float cb = convb[o_old];
#pragma unroll
      for (int mi = 0; mi < 4; ++mi) {
        int rowL = wm + mi * 16 + hi * 4;
#pragma unroll
        for (int r = 0; r < 4; ++r)
          st[(rowL + r) * 136 + colL] = f2bs(acc[mi][ni][r] + cb);
      }
    }
    __syncthreads();
    {
      int cb8  = (t & 15) * 8;
      size_t colg = bn * 128 + cb8;
      size_t rb0  = (size_t)bm * 128;
#pragma unroll
      for (int it = 0; it < 8; ++it) {
        int row = it * 16 + (t >> 4);
        uint4 v = *(const uint4*)(st + row * 136 + cb8);
        *(uint4*)(Pout + (rb0 + row) * ODIM + colg) = v;
      }
    }
#undef STAGE_P
#undef LSA
#undef LSB
  } else {
    // ================= mix role (r4 mix_mfma, row = rid, P = Pin) =================
    int row = rid;
    if (row >= nvalidm) return;
    float* ptsl = (float*)smem;                    // 8 * 264 floats
    int g = w;
    size_t rq = (size_t)bmx * QTOT + q0m + row;
    {
      const float4* ps = (const float4*)(pts + rq * 2048);
#pragma unroll
      for (int i = 0; i < 2; ++i) {
        int v = i * 256 + t;
        float4 val = ps[v];
        int p = v >> 6, c = (v & 63) * 4;
        *(float4*)(ptsl + p * 264 + c) = val;
      }
    }
    __syncthreads();
    int l15 = lane & 15, hi = lane >> 4;
    bf16x8 bfr[2];
#pragma unroll
    for (int kk = 0; kk < 2; ++kk) {
      bf16x8 v = {};
      if (l15 < 8) {
        const float* src = ptsl + l15 * 264 + g * 64 + kk * 32 + hi * 8;
#pragma unroll
        for (int j = 0; j < 8; ++j) v[j] = f2bs(src[j]);
      }
      bfr[kk] = v;
    }
    const __hip_bfloat16* Ap = Pin + (size_t)row * ODIM + g * 4096;
    f32x4 acc[4] = {};
#pragma unroll
    for (int kk = 0; kk < 2; ++kk)
#pragma unroll
      for (int mi = 0; mi < 4; ++mi) {
        bf16x8 a = *(const bf16x8*)(Ap + (size_t)(mi * 16 + l15) * 64 + kk * 32 + hi * 8);
        acc[mi] = __builtin_amdgcn_mfma_f32_16x16x32_bf16(a, bfr[kk], acc[mi], 0, 0, 0);
      }
    float s = 0.f, ss = 0.f;
#pragma unroll
    for (int mi = 0; mi < 4; ++mi)
#pragma unroll
      for (int r = 0; r < 4; ++r) { float v = acc[mi][r]; s += v; ss = fmaf(v, v, ss); }
    s += __shfl_xor(s, 16);  ss += __shfl_xor(ss, 16);
    s += __shfl_xor(s, 32);  ss += __shfl_xor(ss, 32);
    float mu  = s * 0.015625f;
    float var = ss * 0.015625f - mu * mu;
    float rs  = rsqrtf(var + 1e-5f);
    if (l15 < 8) {
      short* ab = (short*)act + ((size_t)g * RTOT + rq) * 512 + l15 * 64;
#pragma unroll
      for (int mi = 0; mi < 4; ++mi) {
        int c2 = mi * 16 + hi * 4;
        float4 gg = *(const float4*)(lng + c2);
        float4 bb = *(const float4*)(lnb + c2);
        short4 o;
        o.x = f2bs(fmaxf(0.f, (acc[mi][0] - mu) * rs * gg.x + bb.x));
        o.y = f2bs(fmaxf(0.f, (acc[mi][1] - mu) * rs * gg.y + bb.y));
        o.z = f2bs(fmaxf(0.f, (acc[mi][2] - mu) * rs * gg.z + bb.z));
        o.w = f2bs(fmaxf(0.f, (acc[mi][3] - mu) * rs * gg.w + bb.w));
        *(short4*)(ab + c2) = o;
      }
    }
  }
}

// ---------------- phase 2b: proj GEMM, direct transposed store to out[b][c][q] ----------------
__global__ __launch_bounds__(256) void gemm_proj(const __hip_bfloat16* __restrict__ act,
                                                 const __hip_bfloat16* __restrict__ Bp,
                                                 const float* __restrict__ projb,
                                                 float* __restrict__ out) {
  __shared__ __align__(16) unsigned char lsA[2][16384];
  __shared__ __align__(16) unsigned char lsB[2][8192];
  int t = threadIdx.x, lane = t & 63, w = t >> 6;
  int bm = blockIdx.x, g = blockIdx.y;
  int wm = (w >> 1) * 64, wn = (w & 1) * 32;
  int srow = lane >> 3;
  int kbs  = ((lane & 7) ^ srow) * 8;
  const __hip_bfloat16* A  = act + (size_t)g * RTOT * 512;
  const __hip_bfloat16* pA = A  + (size_t)(bm * 128 + w * 32 + srow) * 512 + kbs;
  const __hip_bfloat16* pB = Bp + (size_t)(w * 16 + srow) * 512 + kbs;
  f32x4 acc[4][2] = {};

#define STAGE_Q(buf, kt) do {                                                   \
    _Pragma("unroll")                                                           \
    for (int i = 0; i < 4; ++i)                                                 \
      GLOAD_LDS(pA + (size_t)i * 8 * 512 + (kt), lsA[buf] + (w * 4 + i) * 1024); \
    _Pragma("unroll")                                                           \
    for (int j = 0; j < 2; ++j)                                                 \
      GLOAD_LDS(pB + (size_t)j * 8 * 512 + (kt), lsB[buf] + (w * 2 + j) * 1024); \
    } while (0)

  STAGE_Q(0, 0);
  asm volatile("s_waitcnt vmcnt(0)" ::: "memory");
  __builtin_amdgcn_s_barrier();
#pragma unroll
  for (int kt = 0; kt < 8; ++kt) {
    const int cur = kt & 1;
    if (kt < 7) STAGE_Q(cur ^ 1, (kt + 1) * 64);
    __builtin_amdgcn_sched_barrier(0);
#pragma unroll
    for (int kk = 0; kk < 2; ++kk) {
      int kb = kk * 64 + ((lane >> 4) << 4);
      bf16x8 af[4], bfr[2];
#pragma unroll
      for (int mi = 0; mi < 4; ++mi) {
        int row = wm + mi * 16 + (lane & 15);
        af[mi] = *(const bf16x8*)(lsA[cur] + ((row * 128 + kb) ^ ((row & 7) << 4)));
      }
#pragma unroll
      for (int ni = 0; ni < 2; ++ni) {
        int row = wn + ni * 16 + (lane & 15);
        bfr[ni] = *(const bf16x8*)(lsB[cur] + ((row * 128 + kb) ^ ((row & 7) << 4)));
      }
#pragma unroll
      for (int mi = 0; mi < 4; ++mi)
#pragma unroll
        for (int ni = 0; ni < 2; ++ni)
          acc[mi][ni] = __builtin_amdgcn_mfma_f32_16x16x32_bf16(af[mi], bfr[ni], acc[mi][ni], 0, 0, 0);
    }
    __builtin_amdgcn_sched_barrier(0);
    if (kt < 7) asm volatile("s_waitcnt vmcnt(0)" ::: "memory");
    __builtin_amdgcn_s_barrier();
    __builtin_amdgcn_sched_barrier(0);
  }
#pragma unroll
  for (int ni = 0; ni < 2; ++ni) {
    int o = wn + ni * 16 + (lane & 15);
    int c = g * 64 + o;
    float pbv = projb[o];
#pragma unroll
    for (int mi = 0; mi < 4; ++mi) {
      int rg = bm * 128 + wm + mi * 16 + ((lane >> 4) << 2);  // 4 consecutive global rows
      float4 o4;
      o4.x = acc[mi][ni][0] + pbv; o4.y = acc[mi][ni][1] + pbv;
      o4.z = acc[mi][ni][2] + pbv; o4.w = acc[mi][ni][3] + pbv;
      if (rg + 3 < QTOT) {
        *(float4*)(out + (size_t)c * QTOT + rg) = o4;                    // b = 0
      } else if (rg >= QTOT && rg + 3 < 2 * QTOT) {
        *(float4*)(out + (size_t)(CDIM + c) * QTOT + (rg - QTOT)) = o4;  // b = 1
      } else {
#pragma unroll
        for (int r = 0; r < 4; ++r) {
          int q = rg + r;
          if (q < QTOT)          out[(size_t)c * QTOT + q] = (&o4.x)[r];
          else if (q < 2 * QTOT) out[(size_t)(CDIM + c) * QTOT + (q - QTOT)] = (&o4.x)[r];
        }
      }
    }
  }
#undef STAGE_Q
}

extern "C" void kernel_launch(void* const* d_in, const int* in_sizes, int n_in,
                              void* d_out, int out_size, void* d_ws, size_t ws_size,
                              hipStream_t stream) {
  const float* bev = (const float*)d_in[0];
  const float* pts = (const float*)d_in[1];
  const float* cw  = (const float*)d_in[2];
  const float* cb  = (const float*)d_in[3];
  const float* lng = (const float*)d_in[4];
  const float* lnb = (const float*)d_in[5];
  const float* pw  = (const float*)d_in[6];
  const float* pb  = (const float*)d_in[7];
  float* out = (float*)d_out;

  char* ws = (char*)d_ws;
  size_t off = 0;
  auto carve = [&](size_t bytes) -> char* {
    char* p = ws + off;
    off += (bytes + 255) & ~(size_t)255;
    return p;
  };
  __hip_bfloat16* cw_bf = (__hip_bfloat16*)carve((size_t)ODIM * CDIM * 2);
  __hip_bfloat16* bevT  = (__hip_bfloat16*)carve((size_t)2 * MPAD * CDIM * 2);
  __hip_bfloat16* pw_bf = (__hip_bfloat16*)carve((size_t)64 * 512 * 2);
  __hip_bfloat16* act   = (__hip_bfloat16*)carve((size_t)4 * RTOT * 512 * 2);
  size_t fixed = off;

  // chunk rows (multiple of 128); need TWO param buffers (double-buffered across jobs)
  int CH = 128;
  const int ladder[4] = {2560, 1280, 640, 128};
  for (int i = 0; i < 4; ++i) {
    size_t need = fixed + 2 * (((size_t)ladder[i] * ODIM * 2 + 255) & ~(size_t)255);
    if (need <= ws_size) { CH = ladder[i]; break; }
  }
  __hip_bfloat16* paramA = (__hip_bfloat16*)carve((size_t)CH * ODIM * 2);
  __hip_bfloat16* paramB = (__hip_bfloat16*)carve((size_t)CH * ODIM * 2);

  cvt_permute_cw<<<4096, 256, 0, stream>>>(cw, cw_bf, ODIM * CDIM);
  cvt_f32_bf16<<<128, 256, 0, stream>>>(pw, pw_bf, 64 * 512);
  transpose_bev<<<dim3(MPAD / 32, CDIM / 32, 2), dim3(32, 8), 0, stream>>>(bev, bevT);

  int nbm = CH / 128;
  int gemmBlocks = nbm * (ODIM / 128);
  int nchunks = (QTOT + CH - 1) / CH;
  int njobs = 2 * nchunks;
  auto jb = [&](int j) { return j / nchunks; };           // batch of job j
  auto jq = [&](int j) { return (j % nchunks) * CH; };    // q0 of job j
  auto jv = [&](int j) { int nv = QTOT - jq(j); return nv > CH ? CH : nv; };

  for (int j = 0; j <= njobs; ++j) {
    int ngemm = (j < njobs) ? gemmBlocks : 0;
    int nmix  = (j > 0) ? jv(j - 1) : 0;
    __hip_bfloat16* Pout = (j & 1) ? paramB : paramA;
    const __hip_bfloat16* Pin = (j & 1) ? paramA : paramB;
    int bg = 0, q0g = 0, bmx = 0, q0m = 0, nvm = 0;
    if (j < njobs) { bg = jb(j); q0g = jq(j); }
    if (j > 0)     { bmx = jb(j - 1); q0m = jq(j - 1); nvm = jv(j - 1); }
    gemm_mix<<<dim3(ngemm + nmix), 256, 0, stream>>>(bevT, cw_bf, cb, Pout, Pin,
                                                     pts, lng, lnb, act,
                                                     ngemm, nmix, nbm,
                                                     bg, q0g, bmx, q0m, nvm);
  }
  gemm_proj<<<dim3(RTOT / 128, 4), 256, 0, stream>>>(act, pw_bf, pb, out);
}

// Round 18
// 516.728 us; speedup vs baseline: 1.1039x; 1.1039x over previous
//
#include <hip/hip_runtime.h>
#include <hip/hip_bf16.h>
#include <stdint.h>

#define QTOT 10000
#define MPAD 10240
#define CDIM 256
#define ODIM 16384
#define RTOT 20096  // 157*128 : padded global rows (b*10000+q)

using f32x4  = __attribute__((ext_vector_type(4))) float;
using bf16x8 = __attribute__((ext_vector_type(8))) short;

// global -> LDS direct (16B/lane). LDS dest = wave-uniform base + lane*16.
#define GLOAD_LDS(gp, lp) __builtin_amdgcn_global_load_lds(                     \
    (const __attribute__((address_space(1))) unsigned int*)(gp),                \
    (__attribute__((address_space(3))) unsigned int*)(lp), 16, 0, 0)

static __device__ __forceinline__ short f2bs(float x) {
  __hip_bfloat16 h = __float2bfloat16(x);
  return *(short*)&h;
}

// ---------------- prep kernels ----------------
__global__ void cvt_f32_bf16(const float* __restrict__ s, __hip_bfloat16* __restrict__ d, int n) {
  for (int i = blockIdx.x * blockDim.x + threadIdx.x; i < n; i += gridDim.x * blockDim.x)
    d[i] = __float2bfloat16(s[i]);
}

// conv_w row-permute + cvt: dst row o_new = g*4096 + c2*64 + c1  <-  src row g*4096 + c1*64 + c2
__global__ void cvt_permute_cw(const float* __restrict__ s, __hip_bfloat16* __restrict__ d, int n) {
  for (int i = blockIdx.x * blockDim.x + threadIdx.x; i < n; i += gridDim.x * blockDim.x) {
    int rn = i >> 8, c = i & 255;
    int ro = (rn & ~4095) | ((rn & 63) << 6) | ((rn >> 6) & 63);
    d[i] = __float2bfloat16(s[ro * 256 + c]);
  }
}

// bev [b][c][q] f32 -> bevT [b][q][c] bf16, rows q>=QTOT zero-filled up to MPAD
__global__ __launch_bounds__(256) void transpose_bev(const float* __restrict__ bev,
                                                     __hip_bfloat16* __restrict__ bevT) {
  __shared__ float tl[32][33];
  int tx = threadIdx.x, ty = threadIdx.y;
  int q0 = blockIdx.x * 32, c0 = blockIdx.y * 32, b = blockIdx.z;
#pragma unroll
  for (int i = 0; i < 4; ++i) {
    int c = c0 + ty + i * 8, q = q0 + tx;
    tl[ty + i * 8][tx] = (q < QTOT) ? bev[((size_t)b * CDIM + c) * QTOT + q] : 0.0f;
  }
  __syncthreads();
#pragma unroll
  for (int i = 0; i < 4; ++i) {
    int q = q0 + ty + i * 8, c = c0 + tx;
    bevT[((size_t)b * MPAD + q) * CDIM + c] = __float2bfloat16(tl[tx][ty + i * 8]);
  }
}

// ---------------- GEMM1: param[q][o_new] = bevT[q][:] . cw_perm[o_new][:] + cb[o_old] ------
// r14-proven: 128x128, BK=64 dbuf 2-phase, XCD swizzle, coalesced LDS-roundtrip epilogue.
__global__ __launch_bounds__(256) void gemm_param(const __hip_bfloat16* __restrict__ A,
                                                  const __hip_bfloat16* __restrict__ Bw,
                                                  const float* __restrict__ convb,
                                                  __hip_bfloat16* __restrict__ P,
                                                  int nbm) {
  __shared__ __align__(16) unsigned char smem[65536];  // dbuf A(2x16K)+B(2x16K); epilogue reuse
  int t = threadIdx.x, lane = t & 63, w = t >> 6;
  // XCD swizzle (bijective when total%8==0): each XCD gets a contiguous bn-slice.
  int id = blockIdx.x + nbm * blockIdx.y;
  int total = nbm * gridDim.y;
  int nid = (total & 7) ? id : ((id & 7) * (total >> 3) + (id >> 3));
  int bm = nid % nbm, bn = nid / nbm;
  int wm = (w >> 1) * 64, wn = (w & 1) * 64;
  int l15 = lane & 15, hi = lane >> 4;
  int srow = lane >> 3;                  // row within 8-row slab == row&7
  int kbs  = ((lane & 7) ^ srow) * 8;    // pre-swizzled source k-offset (elems)
  const __hip_bfloat16* pA = A  + (size_t)(bm * 128 + w * 32 + srow) * CDIM + kbs;
  const __hip_bfloat16* pB = Bw + (size_t)(bn * 128 + w * 32 + srow) * CDIM + kbs;
  f32x4 acc[4][4] = {};

#define LSA(buf) (smem + (buf) * 16384)
#define LSB(buf) (smem + 32768 + (buf) * 16384)
#define STAGE_P(buf, kt) do {                                                   \
    _Pragma("unroll")                                                           \
    for (int i = 0; i < 4; ++i) {                                               \
      GLOAD_LDS(pA + (size_t)i * 8 * CDIM + (kt), LSA(buf) + (w * 4 + i) * 1024); \
      GLOAD_LDS(pB + (size_t)i * 8 * CDIM + (kt), LSB(buf) + (w * 4 + i) * 1024); \
    } } while (0)

  STAGE_P(0, 0);
  asm volatile("s_waitcnt vmcnt(0)" ::: "memory");
  __builtin_amdgcn_s_barrier();
#pragma unroll
  for (int kt = 0; kt < 4; ++kt) {
    const int cur = kt & 1;
    if (kt < 3) STAGE_P(cur ^ 1, (kt + 1) * 64);
    __builtin_amdgcn_sched_barrier(0);
#pragma unroll
    for (int kk = 0; kk < 2; ++kk) {
      int kb = kk * 64 + (hi << 4);  // byte offset of lane's 8 k-elems
      bf16x8 af[4], bfr[4];
#pragma unroll
      for (int mi = 0; mi < 4; ++mi) {
        int row = wm + mi * 16 + l15;
        af[mi] = *(const bf16x8*)(LSA(cur) + ((row * 128 + kb) ^ ((row & 7) << 4)));
      }
#pragma unroll
      for (int ni = 0; ni < 4; ++ni) {
        int row = wn + ni * 16 + l15;
        bfr[ni] = *(const bf16x8*)(LSB(cur) + ((row * 128 + kb) ^ ((row & 7) << 4)));
      }
#pragma unroll
      for (int mi = 0; mi < 4; ++mi)
#pragma unroll
        for (int ni = 0; ni < 4; ++ni)
          acc[mi][ni] = __builtin_amdgcn_mfma_f32_16x16x32_bf16(af[mi], bfr[ni], acc[mi][ni], 0, 0, 0);
    }
    __builtin_amdgcn_sched_barrier(0);
    if (kt < 3) asm volatile("s_waitcnt vmcnt(0)" ::: "memory");
    __builtin_amdgcn_s_barrier();
    __builtin_amdgcn_sched_barrier(0);
  }
  // ---- coalesced epilogue: acc -> LDS [128 rows][136-short stride] -> dwordx4 stores ----
  short* st = (short*)smem;
#pragma unroll
  for (int ni = 0; ni < 4; ++ni) {
    int colL = wn + ni * 16 + l15;
    int col  = bn * 128 + colL;                               // o_new
    int o_old = (col & ~4095) | ((col & 63) << 6) | ((col >> 6) & 63);
    float cb = convb[o_old];
#pragma unroll
    for (int mi = 0; mi < 4; ++mi) {
      int rowL = wm + mi * 16 + hi * 4;
#pragma unroll
      for (int r = 0; r < 4; ++r)
        st[(rowL + r) * 136 + colL] = f2bs(acc[mi][ni][r] + cb);
    }
  }
  __syncthreads();
  {
    int cb8  = (t & 15) * 8;                                  // 8 bf16 = 16B
    size_t colg = bn * 128 + cb8;
    size_t rb0  = (size_t)bm * 128;
#pragma unroll
    for (int it = 0; it < 8; ++it) {
      int row = it * 16 + (t >> 4);
      uint4 v = *(const uint4*)(st + row * 136 + cb8);
      *(uint4*)(P + (rb0 + row) * ODIM + colg) = v;
    }
  }
#undef STAGE_P
#undef LSA
#undef LSB
}

// ---------------- phase 2a: MFMA mixing + LayerNorm + ReLU (r4-verified) ----------------
// block = 1 pixel, 4 waves = 4 groups. Per wave: mixed^T[c2,p] = param^T[c2,c1] @ pts^T[c1,p]
__global__ __launch_bounds__(256) void mix_mfma(const __hip_bfloat16* __restrict__ P,
                                                const float* __restrict__ pts,
                                                const float* __restrict__ lng,
                                                const float* __restrict__ lnb,
                                                __hip_bfloat16* __restrict__ act,
                                                int b, int q0) {
  __shared__ __align__(16) float ptsl[8 * 264];  // padded rows: 264 f32
  int t = threadIdx.x, lane = t & 63, g = t >> 6;
  int row = blockIdx.x;
  size_t rq = (size_t)b * QTOT + q0 + row;
  {
    const float4* ps = (const float4*)(pts + rq * 2048);
#pragma unroll
    for (int i = 0; i < 2; ++i) {
      int v = i * 256 + t;               // float4 index 0..511
      float4 val = ps[v];
      int p = v >> 6, c = (v & 63) * 4;
      *(float4*)(ptsl + p * 264 + c) = val;
    }
  }
  __syncthreads();
  int l15 = lane & 15, hi = lane >> 4;
  bf16x8 bfr[2];
#pragma unroll
  for (int kk = 0; kk < 2; ++kk) {
    bf16x8 v = {};
    if (l15 < 8) {
      const float* src = ptsl + l15 * 264 + g * 64 + kk * 32 + hi * 8;
#pragma unroll
      for (int j = 0; j < 8; ++j) v[j] = f2bs(src[j]);
    }
    bfr[kk] = v;
  }
  const __hip_bfloat16* Ap = P + (size_t)row * ODIM + g * 4096;
  f32x4 acc[4] = {};
#pragma unroll
  for (int kk = 0; kk < 2; ++kk)
#pragma unroll
    for (int mi = 0; mi < 4; ++mi) {
      bf16x8 a = *(const bf16x8*)(Ap + (size_t)(mi * 16 + l15) * 64 + kk * 32 + hi * 8);
      acc[mi] = __builtin_amdgcn_mfma_f32_16x16x32_bf16(a, bfr[kk], acc[mi], 0, 0, 0);
    }
  // LN over c2 (64 values): 16 regs/lane + reduce across hi (lanes ^16, ^32)
  float s = 0.f, ss = 0.f;
#pragma unroll
  for (int mi = 0; mi < 4; ++mi)
#pragma unroll
    for (int r = 0; r < 4; ++r) { float v = acc[mi][r]; s += v; ss = fmaf(v, v, ss); }
  s += __shfl_xor(s, 16);  ss += __shfl_xor(ss, 16);
  s += __shfl_xor(s, 32);  ss += __shfl_xor(ss, 32);
  float mu  = s * 0.015625f;
  float var = ss * 0.015625f - mu * mu;
  float rs  = rsqrtf(var + 1e-5f);
  if (l15 < 8) {
    short* ab = (short*)act + ((size_t)g * RTOT + rq) * 512 + l15 * 64;
#pragma unroll
    for (int mi = 0; mi < 4; ++mi) {
      int c2 = mi * 16 + hi * 4;
      float4 gg = *(const float4*)(lng + c2);
      float4 bb = *(const float4*)(lnb + c2);
      short4 o;
      o.x = f2bs(fmaxf(0.f, (acc[mi][0] - mu) * rs * gg.x + bb.x));
      o.y = f2bs(fmaxf(0.f, (acc[mi][1] - mu) * rs * gg.y + bb.y));
      o.z = f2bs(fmaxf(0.f, (acc[mi][2] - mu) * rs * gg.z + bb.z));
      o.w = f2bs(fmaxf(0.f, (acc[mi][3] - mu) * rs * gg.w + bb.w));
      *(short4*)(ab + c2) = o;
    }
  }
}

// ---------------- phase 2b: proj GEMM, direct transposed store to out[b][c][q] ----------------
__global__ __launch_bounds__(256) void gemm_proj(const __hip_bfloat16* __restrict__ act,
                                                 const __hip_bfloat16* __restrict__ Bp,
                                                 const float* __restrict__ projb,
                                                 float* __restrict__ out) {
  __shared__ __align__(16) unsigned char lsA[2][16384];
  __shared__ __align__(16) unsigned char lsB[2][8192];
  int t = threadIdx.x, lane = t & 63, w = t >> 6;
  int bm = blockIdx.x, g = blockIdx.y;
  int wm = (w >> 1) * 64, wn = (w & 1) * 32;
  int srow = lane >> 3;
  int kbs  = ((lane & 7) ^ srow) * 8;
  const __hip_bfloat16* A  = act + (size_t)g * RTOT * 512;
  const __hip_bfloat16* pA = A  + (size_t)(bm * 128 + w * 32 + srow) * 512 + kbs;
  const __hip_bfloat16* pB = Bp + (size_t)(w * 16 + srow) * 512 + kbs;
  f32x4 acc[4][2] = {};

#define STAGE_Q(buf, kt) do {                                                   \
    _Pragma("unroll")                                                           \
    for (int i = 0; i < 4; ++i)                                                 \
      GLOAD_LDS(pA + (size_t)i * 8 * 512 + (kt), lsA[buf] + (w * 4 + i) * 1024); \
    _Pragma("unroll")                                                           \
    for (int j = 0; j < 2; ++j)                                                 \
      GLOAD_LDS(pB + (size_t)j * 8 * 512 + (kt), lsB[buf] + (w * 2 + j) * 1024); \
    } while (0)

  STAGE_Q(0, 0);
  asm volatile("s_waitcnt vmcnt(0)" ::: "memory");
  __builtin_amdgcn_s_barrier();
#pragma unroll
  for (int kt = 0; kt < 8; ++kt) {
    const int cur = kt & 1;
    if (kt < 7) STAGE_Q(cur ^ 1, (kt + 1) * 64);
    __builtin_amdgcn_sched_barrier(0);
#pragma unroll
    for (int kk = 0; kk < 2; ++kk) {
      int kb = kk * 64 + ((lane >> 4) << 4);
      bf16x8 af[4], bfr[2];
#pragma unroll
      for (int mi = 0; mi < 4; ++mi) {
        int row = wm + mi * 16 + (lane & 15);
        af[mi] = *(const bf16x8*)(lsA[cur] + ((row * 128 + kb) ^ ((row & 7) << 4)));
      }
#pragma unroll
      for (int ni = 0; ni < 2; ++ni) {
        int row = wn + ni * 16 + (lane & 15);
        bfr[ni] = *(const bf16x8*)(lsB[cur] + ((row * 128 + kb) ^ ((row & 7) << 4)));
      }
#pragma unroll
      for (int mi = 0; mi < 4; ++mi)
#pragma unroll
        for (int ni = 0; ni < 2; ++ni)
          acc[mi][ni] = __builtin_amdgcn_mfma_f32_16x16x32_bf16(af[mi], bfr[ni], acc[mi][ni], 0, 0, 0);
    }
    __builtin_amdgcn_sched_barrier(0);
    if (kt < 7) asm volatile("s_waitcnt vmcnt(0)" ::: "memory");
    __builtin_amdgcn_s_barrier();
    __builtin_amdgcn_sched_barrier(0);
  }
#pragma unroll
  for (int ni = 0; ni < 2; ++ni) {
    int o = wn + ni * 16 + (lane & 15);
    int c = g * 64 + o;
    float pbv = projb[o];
#pragma unroll
    for (int mi = 0; mi < 4; ++mi) {
      int rg = bm * 128 + wm + mi * 16 + ((lane >> 4) << 2);  // 4 consecutive global rows
      float4 o4;
      o4.x = acc[mi][ni][0] + pbv; o4.y = acc[mi][ni][1] + pbv;
      o4.z = acc[mi][ni][2] + pbv; o4.w = acc[mi][ni][3] + pbv;
      if (rg + 3 < QTOT) {
        *(float4*)(out + (size_t)c * QTOT + rg) = o4;                    // b = 0
      } else if (rg >= QTOT && rg + 3 < 2 * QTOT) {
        *(float4*)(out + (size_t)(CDIM + c) * QTOT + (rg - QTOT)) = o4;  // b = 1
      } else {
#pragma unroll
        for (int r = 0; r < 4; ++r) {
          int q = rg + r;
          if (q < QTOT)          out[(size_t)c * QTOT + q] = (&o4.x)[r];
          else if (q < 2 * QTOT) out[(size_t)(CDIM + c) * QTOT + (q - QTOT)] = (&o4.x)[r];
        }
      }
    }
  }
#undef STAGE_Q
}

extern "C" void kernel_launch(void* const* d_in, const int* in_sizes, int n_in,
                              void* d_out, int out_size, void* d_ws, size_t ws_size,
                              hipStream_t stream) {
  const float* bev = (const float*)d_in[0];
  const float* pts = (const float*)d_in[1];
  const float* cw  = (const float*)d_in[2];
  const float* cb  = (const float*)d_in[3];
  const float* lng = (const float*)d_in[4];
  const float* lnb = (const float*)d_in[5];
  const float* pw  = (const float*)d_in[6];
  const float* pb  = (const float*)d_in[7];
  float* out = (float*)d_out;

  char* ws = (char*)d_ws;
  size_t off = 0;
  auto carve = [&](size_t bytes) -> char* {
    char* p = ws + off;
    off += (bytes + 255) & ~(size_t)255;
    return p;
  };
  __hip_bfloat16* cw_bf = (__hip_bfloat16*)carve((size_t)ODIM * CDIM * 2);
  __hip_bfloat16* bevT  = (__hip_bfloat16*)carve((size_t)2 * MPAD * CDIM * 2);
  __hip_bfloat16* pw_bf = (__hip_bfloat16*)carve((size_t)64 * 512 * 2);
  __hip_bfloat16* act   = (__hip_bfloat16*)carve((size_t)4 * RTOT * 512 * 2);
  size_t fixed = off;

  // chunk rows (multiple of 128). CH=5120 (168MB, L3-fits) halves launch count vs 2560;
  // r13's bad 5120 datum was confounded by the scalar-store epilogue (since fixed, r14).
  int CH = 128;
  const int ladder[5] = {5120, 2560, 1280, 640, 128};
  for (int i = 0; i < 5; ++i) {
    size_t need = fixed + (((size_t)ladder[i] * ODIM * 2 + 255) & ~(size_t)255);
    if (need <= ws_size) { CH = ladder[i]; break; }
  }
  __hip_bfloat16* param = (__hip_bfloat16*)carve((size_t)CH * ODIM * 2);

  cvt_permute_cw<<<4096, 256, 0, stream>>>(cw, cw_bf, ODIM * CDIM);
  cvt_f32_bf16<<<128, 256, 0, stream>>>(pw, pw_bf, 64 * 512);
  transpose_bev<<<dim3(MPAD / 32, CDIM / 32, 2), dim3(32, 8), 0, stream>>>(bev, bevT);

  int nbm = CH / 128;
  int nchunks = (QTOT + CH - 1) / CH;
  for (int b = 0; b < 2; ++b) {
    for (int c = 0; c < nchunks; ++c) {
      int q0 = c * CH;
      int nvalid = QTOT - q0;
      if (nvalid > CH) nvalid = CH;
      const __hip_bfloat16* Ab = bevT + ((size_t)b * MPAD + q0) * CDIM;
      gemm_param<<<dim3(nbm, ODIM / 128), 256, 0, stream>>>(Ab, cw_bf, cb, param, nbm);
      mix_mfma<<<dim3(nvalid), 256, 0, stream>>>(param, pts, lng, lnb, act, b, q0);
    }
  }
  gemm_proj<<<dim3(RTOT / 128, 4), 256, 0, stream>>>(act, pw_bf, pb, out);
}

// Round 19
// 510.262 us; speedup vs baseline: 1.1179x; 1.0127x over previous
//
#include <hip/hip_runtime.h>
#include <hip/hip_bf16.h>
#include <stdint.h>

#define QTOT 10000
#define MPAD 10240
#define CDIM 256
#define ODIM 16384
#define RTOT 20096  // 157*128 : padded global rows (b*10000+q)

using f32x4  = __attribute__((ext_vector_type(4))) float;
using bf16x8 = __attribute__((ext_vector_type(8))) short;

// global -> LDS direct (16B/lane). LDS dest = wave-uniform base + lane*16.
#define GLOAD_LDS(gp, lp) __builtin_amdgcn_global_load_lds(                     \
    (const __attribute__((address_space(1))) unsigned int*)(gp),                \
    (__attribute__((address_space(3))) unsigned int*)(lp), 16, 0, 0)

static __device__ __forceinline__ short f2bs(float x) {
  __hip_bfloat16 h = __float2bfloat16(x);
  return *(short*)&h;
}

// ---------------- prep kernels ----------------
__global__ void cvt_f32_bf16(const float* __restrict__ s, __hip_bfloat16* __restrict__ d, int n) {
  for (int i = blockIdx.x * blockDim.x + threadIdx.x; i < n; i += gridDim.x * blockDim.x)
    d[i] = __float2bfloat16(s[i]);
}

// conv_w row-permute + cvt: dst row o_new = g*4096 + c2*64 + c1  <-  src row g*4096 + c1*64 + c2
__global__ void cvt_permute_cw(const float* __restrict__ s, __hip_bfloat16* __restrict__ d, int n) {
  for (int i = blockIdx.x * blockDim.x + threadIdx.x; i < n; i += gridDim.x * blockDim.x) {
    int rn = i >> 8, c = i & 255;
    int ro = (rn & ~4095) | ((rn & 63) << 6) | ((rn >> 6) & 63);
    d[i] = __float2bfloat16(s[ro * 256 + c]);
  }
}

// bev [b][c][q] f32 -> bevT [b][q][c] bf16, rows q>=QTOT zero-filled up to MPAD
__global__ __launch_bounds__(256) void transpose_bev(const float* __restrict__ bev,
                                                     __hip_bfloat16* __restrict__ bevT) {
  __shared__ float tl[32][33];
  int tx = threadIdx.x, ty = threadIdx.y;
  int q0 = blockIdx.x * 32, c0 = blockIdx.y * 32, b = blockIdx.z;
#pragma unroll
  for (int i = 0; i < 4; ++i) {
    int c = c0 + ty + i * 8, q = q0 + tx;
    tl[ty + i * 8][tx] = (q < QTOT) ? bev[((size_t)b * CDIM + c) * QTOT + q] : 0.0f;
  }
  __syncthreads();
#pragma unroll
  for (int i = 0; i < 4; ++i) {
    int q = q0 + ty + i * 8, c = c0 + tx;
    bevT[((size_t)b * MPAD + q) * CDIM + c] = __float2bfloat16(tl[tx][ty + i * 8]);
  }
}

// ---------------- GEMM1: param[q][o_new] = bevT[q][:] . cw_perm[o_new][:] + cb[o_old] ------
// r14-proven: 128x128, BK=64 dbuf 2-phase, XCD swizzle, coalesced LDS-roundtrip epilogue.
__global__ __launch_bounds__(256) void gemm_param(const __hip_bfloat16* __restrict__ A,
                                                  const __hip_bfloat16* __restrict__ Bw,
                                                  const float* __restrict__ convb,
                                                  __hip_bfloat16* __restrict__ P,
                                                  int nbm) {
  __shared__ __align__(16) unsigned char smem[65536];  // dbuf A(2x16K)+B(2x16K); epilogue reuse
  int t = threadIdx.x, lane = t & 63, w = t >> 6;
  // XCD swizzle (bijective when total%8==0): each XCD gets a contiguous bn-slice.
  int id = blockIdx.x + nbm * blockIdx.y;
  int total = nbm * gridDim.y;
  int nid = (total & 7) ? id : ((id & 7) * (total >> 3) + (id >> 3));
  int bm = nid % nbm, bn = nid / nbm;
  int wm = (w >> 1) * 64, wn = (w & 1) * 64;
  int l15 = lane & 15, hi = lane >> 4;
  int srow = lane >> 3;                  // row within 8-row slab == row&7
  int kbs  = ((lane & 7) ^ srow) * 8;    // pre-swizzled source k-offset (elems)
  const __hip_bfloat16* pA = A  + (size_t)(bm * 128 + w * 32 + srow) * CDIM + kbs;
  const __hip_bfloat16* pB = Bw + (size_t)(bn * 128 + w * 32 + srow) * CDIM + kbs;
  f32x4 acc[4][4] = {};

#define LSA(buf) (smem + (buf) * 16384)
#define LSB(buf) (smem + 32768 + (buf) * 16384)
#define STAGE_P(buf, kt) do {                                                   \
    _Pragma("unroll")                                                           \
    for (int i = 0; i < 4; ++i) {                                               \
      GLOAD_LDS(pA + (size_t)i * 8 * CDIM + (kt), LSA(buf) + (w * 4 + i) * 1024); \
      GLOAD_LDS(pB + (size_t)i * 8 * CDIM + (kt), LSB(buf) + (w * 4 + i) * 1024); \
    } } while (0)

  STAGE_P(0, 0);
  asm volatile("s_waitcnt vmcnt(0)" ::: "memory");
  __builtin_amdgcn_s_barrier();
#pragma unroll
  for (int kt = 0; kt < 4; ++kt) {
    const int cur = kt & 1;
    if (kt < 3) STAGE_P(cur ^ 1, (kt + 1) * 64);
    __builtin_amdgcn_sched_barrier(0);
#pragma unroll
    for (int kk = 0; kk < 2; ++kk) {
      int kb = kk * 64 + (hi << 4);  // byte offset of lane's 8 k-elems
      bf16x8 af[4], bfr[4];
#pragma unroll
      for (int mi = 0; mi < 4; ++mi) {
        int row = wm + mi * 16 + l15;
        af[mi] = *(const bf16x8*)(LSA(cur) + ((row * 128 + kb) ^ ((row & 7) << 4)));
      }
#pragma unroll
      for (int ni = 0; ni < 4; ++ni) {
        int row = wn + ni * 16 + l15;
        bfr[ni] = *(const bf16x8*)(LSB(cur) + ((row * 128 + kb) ^ ((row & 7) << 4)));
      }
#pragma unroll
      for (int mi = 0; mi < 4; ++mi)
#pragma unroll
        for (int ni = 0; ni < 4; ++ni)
          acc[mi][ni] = __builtin_amdgcn_mfma_f32_16x16x32_bf16(af[mi], bfr[ni], acc[mi][ni], 0, 0, 0);
    }
    __builtin_amdgcn_sched_barrier(0);
    if (kt < 3) asm volatile("s_waitcnt vmcnt(0)" ::: "memory");
    __builtin_amdgcn_s_barrier();
    __builtin_amdgcn_sched_barrier(0);
  }
  // ---- coalesced epilogue: acc -> LDS [128 rows][136-short stride] -> dwordx4 stores ----
  short* st = (short*)smem;
#pragma unroll
  for (int ni = 0; ni < 4; ++ni) {
    int colL = wn + ni * 16 + l15;
    int col  = bn * 128 + colL;                               // o_new
    int o_old = (col & ~4095) | ((col & 63) << 6) | ((col >> 6) & 63);
    float cb = convb[o_old];
#pragma unroll
    for (int mi = 0; mi < 4; ++mi) {
      int rowL = wm + mi * 16 + hi * 4;
#pragma unroll
      for (int r = 0; r < 4; ++r)
        st[(rowL + r) * 136 + colL] = f2bs(acc[mi][ni][r] + cb);
    }
  }
  __syncthreads();
  {
    int cb8  = (t & 15) * 8;                                  // 8 bf16 = 16B
    size_t colg = bn * 128 + cb8;
    size_t rb0  = (size_t)bm * 128;
#pragma unroll
    for (int it = 0; it < 8; ++it) {
      int row = it * 16 + (t >> 4);
      uint4 v = *(const uint4*)(st + row * 136 + cb8);
      *(uint4*)(P + (rb0 + row) * ODIM + colg) = v;
    }
  }
#undef STAGE_P
#undef LSA
#undef LSB
}

// ---------------- phase 2a: MFMA mixing + LayerNorm + ReLU (r4-verified) ----------------
// block = 1 pixel, 4 waves = 4 groups. Per wave: mixed^T[c2,p] = param^T[c2,c1] @ pts^T[c1,p]
__global__ __launch_bounds__(256) void mix_mfma(const __hip_bfloat16* __restrict__ P,
                                                const float* __restrict__ pts,
                                                const float* __restrict__ lng,
                                                const float* __restrict__ lnb,
                                                __hip_bfloat16* __restrict__ act,
                                                int b, int q0) {
  __shared__ __align__(16) float ptsl[8 * 264];  // padded rows: 264 f32
  int t = threadIdx.x, lane = t & 63, g = t >> 6;
  int row = blockIdx.x;
  size_t rq = (size_t)b * QTOT + q0 + row;
  {
    const float4* ps = (const float4*)(pts + rq * 2048);
#pragma unroll
    for (int i = 0; i < 2; ++i) {
      int v = i * 256 + t;               // float4 index 0..511
      float4 val = ps[v];
      int p = v >> 6, c = (v & 63) * 4;
      *(float4*)(ptsl + p * 264 + c) = val;
    }
  }
  __syncthreads();
  int l15 = lane & 15, hi = lane >> 4;
  bf16x8 bfr[2];
#pragma unroll
  for (int kk = 0; kk < 2; ++kk) {
    bf16x8 v = {};
    if (l15 < 8) {
      const float* src = ptsl + l15 * 264 + g * 64 + kk * 32 + hi * 8;
#pragma unroll
      for (int j = 0; j < 8; ++j) v[j] = f2bs(src[j]);
    }
    bfr[kk] = v;
  }
  const __hip_bfloat16* Ap = P + (size_t)row * ODIM + g * 4096;
  f32x4 acc[4] = {};
#pragma unroll
  for (int kk = 0; kk < 2; ++kk)
#pragma unroll
    for (int mi = 0; mi < 4; ++mi) {
      bf16x8 a = *(const bf16x8*)(Ap + (size_t)(mi * 16 + l15) * 64 + kk * 32 + hi * 8);
      acc[mi] = __builtin_amdgcn_mfma_f32_16x16x32_bf16(a, bfr[kk], acc[mi], 0, 0, 0);
    }
  // LN over c2 (64 values): 16 regs/lane + reduce across hi (lanes ^16, ^32)
  float s = 0.f, ss = 0.f;
#pragma unroll
  for (int mi = 0; mi < 4; ++mi)
#pragma unroll
    for (int r = 0; r < 4; ++r) { float v = acc[mi][r]; s += v; ss = fmaf(v, v, ss); }
  s += __shfl_xor(s, 16);  ss += __shfl_xor(ss, 16);
  s += __shfl_xor(s, 32);  ss += __shfl_xor(ss, 32);
  float mu  = s * 0.015625f;
  float var = ss * 0.015625f - mu * mu;
  float rs  = rsqrtf(var + 1e-5f);
  if (l15 < 8) {
    short* ab = (short*)act + ((size_t)g * RTOT + rq) * 512 + l15 * 64;
#pragma unroll
    for (int mi = 0; mi < 4; ++mi) {
      int c2 = mi * 16 + hi * 4;
      float4 gg = *(const float4*)(lng + c2);
      float4 bb = *(const float4*)(lnb + c2);
      short4 o;
      o.x = f2bs(fmaxf(0.f, (acc[mi][0] - mu) * rs * gg.x + bb.x));
      o.y = f2bs(fmaxf(0.f, (acc[mi][1] - mu) * rs * gg.y + bb.y));
      o.z = f2bs(fmaxf(0.f, (acc[mi][2] - mu) * rs * gg.z + bb.z));
      o.w = f2bs(fmaxf(0.f, (acc[mi][3] - mu) * rs * gg.w + bb.w));
      *(short4*)(ab + c2) = o;
    }
  }
}

// ---------------- phase 2b: proj GEMM, direct transposed store to out[b][c][q] ----------------
__global__ __launch_bounds__(256) void gemm_proj(const __hip_bfloat16* __restrict__ act,
                                                 const __hip_bfloat16* __restrict__ Bp,
                                                 const float* __restrict__ projb,
                                                 float* __restrict__ out) {
  __shared__ __align__(16) unsigned char lsA[2][16384];
  __shared__ __align__(16) unsigned char lsB[2][8192];
  int t = threadIdx.x, lane = t & 63, w = t >> 6;
  int bm = blockIdx.x, g = blockIdx.y;
  int wm = (w >> 1) * 64, wn = (w & 1) * 32;
  int srow = lane >> 3;
  int kbs  = ((lane & 7) ^ srow) * 8;
  const __hip_bfloat16* A  = act + (size_t)g * RTOT * 512;
  const __hip_bfloat16* pA = A  + (size_t)(bm * 128 + w * 32 + srow) * 512 + kbs;
  const __hip_bfloat16* pB = Bp + (size_t)(w * 16 + srow) * 512 + kbs;
  f32x4 acc[4][2] = {};

#define STAGE_Q(buf, kt) do {                                                   \
    _Pragma("unroll")                                                           \
    for (int i = 0; i < 4; ++i)                                                 \
      GLOAD_LDS(pA + (size_t)i * 8 * 512 + (kt), lsA[buf] + (w * 4 + i) * 1024); \
    _Pragma("unroll")                                                           \
    for (int j = 0; j < 2; ++j)                                                 \
      GLOAD_LDS(pB + (size_t)j * 8 * 512 + (kt), lsB[buf] + (w * 2 + j) * 1024); \
    } while (0)

  STAGE_Q(0, 0);
  asm volatile("s_waitcnt vmcnt(0)" ::: "memory");
  __builtin_amdgcn_s_barrier();
#pragma unroll
  for (int kt = 0; kt < 8; ++kt) {
    const int cur = kt & 1;
    if (kt < 7) STAGE_Q(cur ^ 1, (kt + 1) * 64);
    __builtin_amdgcn_sched_barrier(0);
#pragma unroll
    for (int kk = 0; kk < 2; ++kk) {
      int kb = kk * 64 + ((lane >> 4) << 4);
      bf16x8 af[4], bfr[2];
#pragma unroll
      for (int mi = 0; mi < 4; ++mi) {
        int row = wm + mi * 16 + (lane & 15);
        af[mi] = *(const bf16x8*)(lsA[cur] + ((row * 128 + kb) ^ ((row & 7) << 4)));
      }
#pragma unroll
      for (int ni = 0; ni < 2; ++ni) {
        int row = wn + ni * 16 + (lane & 15);
        bfr[ni] = *(const bf16x8*)(lsB[cur] + ((row * 128 + kb) ^ ((row & 7) << 4)));
      }
#pragma unroll
      for (int mi = 0; mi < 4; ++mi)
#pragma unroll
        for (int ni = 0; ni < 2; ++ni)
          acc[mi][ni] = __builtin_amdgcn_mfma_f32_16x16x32_bf16(af[mi], bfr[ni], acc[mi][ni], 0, 0, 0);
    }
    __builtin_amdgcn_sched_barrier(0);
    if (kt < 7) asm volatile("s_waitcnt vmcnt(0)" ::: "memory");
    __builtin_amdgcn_s_barrier();
    __builtin_amdgcn_sched_barrier(0);
  }
#pragma unroll
  for (int ni = 0; ni < 2; ++ni) {
    int o = wn + ni * 16 + (lane & 15);
    int c = g * 64 + o;
    float pbv = projb[o];
#pragma unroll
    for (int mi = 0; mi < 4; ++mi) {
      int rg = bm * 128 + wm + mi * 16 + ((lane >> 4) << 2);  // 4 consecutive global rows
      float4 o4;
      o4.x = acc[mi][ni][0] + pbv; o4.y = acc[mi][ni][1] + pbv;
      o4.z = acc[mi][ni][2] + pbv; o4.w = acc[mi][ni][3] + pbv;
      if (rg + 3 < QTOT) {
        *(float4*)(out + (size_t)c * QTOT + rg) = o4;                    // b = 0
      } else if (rg >= QTOT && rg + 3 < 2 * QTOT) {
        *(float4*)(out + (size_t)(CDIM + c) * QTOT + (rg - QTOT)) = o4;  // b = 1
      } else {
#pragma unroll
        for (int r = 0; r < 4; ++r) {
          int q = rg + r;
          if (q < QTOT)          out[(size_t)c * QTOT + q] = (&o4.x)[r];
          else if (q < 2 * QTOT) out[(size_t)(CDIM + c) * QTOT + (q - QTOT)] = (&o4.x)[r];
        }
      }
    }
  }
#undef STAGE_Q
}

extern "C" void kernel_launch(void* const* d_in, const int* in_sizes, int n_in,
                              void* d_out, int out_size, void* d_ws, size_t ws_size,
                              hipStream_t stream) {
  const float* bev = (const float*)d_in[0];
  const float* pts = (const float*)d_in[1];
  const float* cw  = (const float*)d_in[2];
  const float* cb  = (const float*)d_in[3];
  const float* lng = (const float*)d_in[4];
  const float* lnb = (const float*)d_in[5];
  const float* pw  = (const float*)d_in[6];
  const float* pb  = (const float*)d_in[7];
  float* out = (float*)d_out;

  char* ws = (char*)d_ws;
  size_t off = 0;
  auto carve = [&](size_t bytes) -> char* {
    char* p = ws + off;
    off += (bytes + 255) & ~(size_t)255;
    return p;
  };
  __hip_bfloat16* cw_bf = (__hip_bfloat16*)carve((size_t)ODIM * CDIM * 2);
  __hip_bfloat16* bevT  = (__hip_bfloat16*)carve((size_t)2 * MPAD * CDIM * 2);
  __hip_bfloat16* pw_bf = (__hip_bfloat16*)carve((size_t)64 * 512 * 2);
  __hip_bfloat16* act   = (__hip_bfloat16*)carve((size_t)4 * RTOT * 512 * 2);
  size_t fixed = off;

  // chunk rows (multiple of 128); 2560 (84MB chunk, L3-resident) is the measured best
  // (r18: CH=5120 pushed param writes to HBM -> 517us vs 511us).
  int CH = 128;
  const int ladder[4] = {2560, 1280, 640, 128};
  for (int i = 0; i < 4; ++i) {
    size_t need = fixed + (((size_t)ladder[i] * ODIM * 2 + 255) & ~(size_t)255);
    if (need <= ws_size) { CH = ladder[i]; break; }
  }
  __hip_bfloat16* param = (__hip_bfloat16*)carve((size_t)CH * ODIM * 2);

  cvt_permute_cw<<<4096, 256, 0, stream>>>(cw, cw_bf, ODIM * CDIM);
  cvt_f32_bf16<<<128, 256, 0, stream>>>(pw, pw_bf, 64 * 512);
  transpose_bev<<<dim3(MPAD / 32, CDIM / 32, 2), dim3(32, 8), 0, stream>>>(bev, bevT);

  int nbm = CH / 128;
  int nchunks = (QTOT + CH - 1) / CH;
  for (int b = 0; b < 2; ++b) {
    for (int c = 0; c < nchunks; ++c) {
      int q0 = c * CH;
      int nvalid = QTOT - q0;
      if (nvalid > CH) nvalid = CH;
      const __hip_bfloat16* Ab = bevT + ((size_t)b * MPAD + q0) * CDIM;
      gemm_param<<<dim3(nbm, ODIM / 128), 256, 0, stream>>>(Ab, cw_bf, cb, param, nbm);
      mix_mfma<<<dim3(nvalid), 256, 0, stream>>>(param, pts, lng, lnb, act, b, q0);
    }
  }
  gemm_proj<<<dim3(RTOT / 128, 4), 256, 0, stream>>>(act, pw_bf, pb, out);
}